// Round 22
// baseline (92.402 us; speedup 1.0000x reference)
//
#include <hip/hip_runtime.h>
#include <hip/hip_bf16.h>

namespace {

typedef unsigned short u16;
typedef __attribute__((ext_vector_type(8))) short bf16x8;
typedef __attribute__((ext_vector_type(4))) float f32x4;

constexpr int kB = 8, kT = 2048, kC = 1024, kH = 64;
constexpr float kScale = 0.03125f;  // 1024^-0.5

// workspace layout in u16 elements
constexpr size_t kWtOff = 0;                                 // 3*64*1024
constexpr size_t kQbOff = kWtOff + 3 * 64 * 1024;            // 16384*64
constexpr size_t kKbOff = kQbOff + (size_t)16384 * 64;
constexpr size_t kVtOff = kKbOff + (size_t)16384 * 64;       // v^T [b*64+h][t]
constexpr size_t kLOff  = kVtOff + (size_t)16384 * 64;       // float l[16384]
constexpr size_t kPartOff = kLOff + (size_t)16384 * 2;       // float part[4][1M]

__device__ __forceinline__ u16 f2bu(float f) {
  __hip_bfloat16 h = __float2bfloat16(f);
  return *reinterpret_cast<u16*>(&h);
}
__device__ __forceinline__ f32x4 mfma16(bf16x8 a, bf16x8 b, f32x4 c) {
  return __builtin_amdgcn_mfma_f32_16x16x32_bf16(a, b, c, 0, 0, 0);
}

__global__ __launch_bounds__(256) void zero_l_kernel(float* __restrict__ l) {
  l[blockIdx.x * 256 + threadIdx.x] = 0.f;
}

// K0: Wt[mat][h][c] = bf16(W[c][h])  (rows indexed by ncol = mat*64+h)
__global__ __launch_bounds__(256) void wt_kernel(
    const float* __restrict__ Wk, const float* __restrict__ Wq,
    const float* __restrict__ Wv, u16* __restrict__ Wt) {
  __shared__ float wsm[64 * 65];
  const int c0 = blockIdx.x * 64;
  const int mat = blockIdx.y;
  const float* W = (mat == 0) ? Wk : (mat == 1) ? Wq : Wv;
  const int tid = threadIdx.x;
#pragma unroll
  for (int ii = 0; ii < 4; ++ii) {
    const int p = tid + 256 * ii;
    const int row = p >> 4, col4 = p & 15;
    const float4 wv = *reinterpret_cast<const float4*>(&W[(size_t)(c0 + row) * 64 + col4 * 4]);
    wsm[row * 65 + col4 * 4 + 0] = wv.x;
    wsm[row * 65 + col4 * 4 + 1] = wv.y;
    wsm[row * 65 + col4 * 4 + 2] = wv.z;
    wsm[row * 65 + col4 * 4 + 3] = wv.w;
  }
  __syncthreads();
  const int h = tid & 63, seg = tid >> 6;
#pragma unroll
  for (int i = 0; i < 16; ++i) {
    const int c = seg * 16 + i;
    Wt[((size_t)mat * 64 + h) * 1024 + c0 + c] = f2bu(wsm[c * 65 + h]);
  }
}

// K1: fused q,k,v GEMM.  BM=64 (256 blocks = 1/CU), 8 waves (512 thr),
// 8 K-phases of 128.  Per phase: cooperative bulk-fill of W[192][128]
// (48 KiB, HALF the total fill work of BM=32) + x[64][128] (16 KiB) into
// swizzled LDS, then pure-LDS MFMA (24/wave).
// Wave w = (mi = w&3 -> 16-row m-frag, nw = w>>2 -> 96-col group).
__global__ __launch_bounds__(512) void qkv_kernel(
    const float* __restrict__ x, const u16* __restrict__ Wt,
    u16* __restrict__ qb, u16* __restrict__ kb, u16* __restrict__ vt) {
  __shared__ u16 wl[192 * 128];  // 48 KiB, XOR-swizzled (u16-idx bits 3-5 ^ row&7)
  __shared__ u16 xl[64 * 128];   // 16 KiB, same swizzle
  const int tid = threadIdx.x;
  const int lane = tid & 63, w = tid >> 6;
  const int l15 = lane & 15, l4 = lane >> 4;
  const int mi = w & 3, nw = w >> 2;
  const int m0 = blockIdx.x * 64;

  f32x4 acc[6];
#pragma unroll
  for (int ni = 0; ni < 6; ++ni) acc[ni] = f32x4{0.f, 0.f, 0.f, 0.f};

  for (int p = 0; p < 8; ++p) {
    const int k0 = p * 128;
    __syncthreads();
#pragma unroll
    for (int i = 0; i < 6; ++i) {
      const int q = tid + 512 * i;
      const int row = q >> 4, c8 = (q & 15) * 8;
      const uint4 wv = *reinterpret_cast<const uint4*>(&Wt[(size_t)row * 1024 + k0 + c8]);
      *reinterpret_cast<uint4*>(&wl[(row * 128 + c8) ^ ((row & 7) << 3)]) = wv;
    }
#pragma unroll
    for (int i = 0; i < 4; ++i) {
      const int q = tid + 512 * i;
      const int row = q >> 5, c4 = (q & 31) * 4;
      const float4 xv = *reinterpret_cast<const float4*>(&x[(size_t)(m0 + row) * kC + k0 + c4]);
      uint2 pk;
      pk.x = (unsigned)f2bu(xv.x) | ((unsigned)f2bu(xv.y) << 16);
      pk.y = (unsigned)f2bu(xv.z) | ((unsigned)f2bu(xv.w) << 16);
      *reinterpret_cast<uint2*>(&xl[(row * 128 + c4) ^ ((row & 7) << 3)]) = pk;
    }
    __syncthreads();
#pragma unroll
    for (int ks = 0; ks < 4; ++ks) {
      const int kk = ks * 32 + 8 * l4;
      const int arow = 16 * mi + l15;
      const bf16x8 a =
          *reinterpret_cast<const bf16x8*>(&xl[(arow * 128 + kk) ^ ((arow & 7) << 3)]);
#pragma unroll
      for (int ni = 0; ni < 6; ++ni) {
        const int row = 96 * nw + 16 * ni + l15;
        const bf16x8 bfr =
            *reinterpret_cast<const bf16x8*>(&wl[(row * 128 + kk) ^ ((row & 7) << 3)]);
        acc[ni] = mfma16(a, bfr, acc[ni]);
      }
    }
  }
#pragma unroll
  for (int ni = 0; ni < 6; ++ni) {
    const int ncol = 96 * nw + 16 * ni + l15;
    const int mat = ncol >> 6, h = ncol & 63;
#pragma unroll
    for (int r = 0; r < 4; ++r) {
      const int m = m0 + 16 * mi + 4 * l4 + r;
      const u16 val = f2bu(acc[ni][r]);
      if (mat == 0) kb[(size_t)m * 64 + h] = val;
      else if (mat == 1) qb[(size_t)m * 64 + h] = val;
      else vt[((size_t)((m >> 11) * 64 + h)) * 2048 + (m & 2047)] = val;
    }
  }
}

// K2: l[b,s] = sum_{t>=s} exp(scale * q_t.k_s).  mfma(A=K, B=Q) -> D[s][t].
__global__ __launch_bounds__(256) void colsum_kernel(
    const u16* __restrict__ qb, const u16* __restrict__ kb, float* __restrict__ lG) {
  const int bid = blockIdx.x;
  const int b = bid & 7;
  const int rr = bid >> 3;
  const int s0 = (rr & 31) * 64;
  const int tc = (rr >> 5) * 512;
  if (tc + 511 < s0) return;
  const int tid = threadIdx.x;
  const int lane = tid & 63, w = tid >> 6;
  const int l15 = lane & 15, l4 = lane >> 4;

  bf16x8 ka[4][2];
#pragma unroll
  for (int i = 0; i < 4; ++i) {
    const u16* kp = kb + (size_t)(b * kT + s0 + 16 * i + l15) * 64 + 8 * l4;
    ka[i][0] = *reinterpret_cast<const bf16x8*>(kp);
    ka[i][1] = *reinterpret_cast<const bf16x8*>(kp + 32);
  }
  f32x4 cs[4];
#pragma unroll
  for (int i = 0; i < 4; ++i) cs[i] = f32x4{0.f, 0.f, 0.f, 0.f};

  const int d0 = s0 - tc - 128 * w;
  const int jstart = (d0 > 0) ? (d0 >> 4) : 0;
  const u16* qbase = qb + (size_t)(b * kT + tc + 128 * w + l15) * 64 + 8 * l4;
  bf16x8 qf0, qf1;
  if (jstart < 8) {
    qf0 = *reinterpret_cast<const bf16x8*>(qbase + (size_t)jstart * 1024);
    qf1 = *reinterpret_cast<const bf16x8*>(qbase + (size_t)jstart * 1024 + 32);
  }
  for (int j = jstart; j < 8; ++j) {
    bf16x8 qn0, qn1;
    if (j < 7) {
      qn0 = *reinterpret_cast<const bf16x8*>(qbase + (size_t)(j + 1) * 1024);
      qn1 = *reinterpret_cast<const bf16x8*>(qbase + (size_t)(j + 1) * 1024 + 32);
    }
    const int t = tc + 128 * w + 16 * j + l15;
#pragma unroll
    for (int i = 0; i < 4; ++i) {
      f32x4 d = f32x4{0.f, 0.f, 0.f, 0.f};
      d = mfma16(ka[i][0], qf0, d);
      d = mfma16(ka[i][1], qf1, d);
#pragma unroll
      for (int r = 0; r < 4; ++r) {
        const int s = s0 + 16 * i + 4 * l4 + r;
        if (t >= s) cs[i][r] += __expf(d[r] * kScale);
      }
    }
    qf0 = qn0; qf1 = qn1;
  }
#pragma unroll
  for (int i = 0; i < 4; ++i) {
#pragma unroll
    for (int r = 0; r < 4; ++r) {
      float v = cs[i][r];
      v += __shfl_xor(v, 1, 64);
      v += __shfl_xor(v, 2, 64);
      v += __shfl_xor(v, 4, 64);
      v += __shfl_xor(v, 8, 64);
      if (l15 == 0) atomicAdd(&lG[b * kT + s0 + 16 * i + 4 * l4 + r], v);
    }
  }
}

// K3a: partial PV over one s-quarter.  Block = (b, 128-row t-tile tt, quarter
// q4): 512 blocks x 8 waves.  Per s-tile of 64: cooperative LDS stage of
// k[64][64] + v^T[64][64], swapped QK^T -> (exp * rcp(l)) -> shuffle
// transpose -> PV.  1/l folded here.  part[q4][b][t][h].
__global__ __launch_bounds__(512, 4) void out_part_kernel(
    const u16* __restrict__ qb, const u16* __restrict__ kb, const u16* __restrict__ vt,
    const float* __restrict__ lG, float* __restrict__ part) {
  __shared__ u16 kl[64 * 64];  // 8 KiB, XOR-swizzled
  __shared__ u16 vl[64 * 64];  // 8 KiB, XOR-swizzled
  const int bid = blockIdx.x;
  const int b = bid & 7;            // batch-per-XCD L2 locality
  const int q4 = (bid >> 3) & 3;    // s-quarter
  const int tt = bid >> 5;          // 0..15
  const int t0 = tt * 128;
  const int tid = threadIdx.x;
  const int lane = tid & 63, w = tid >> 6;
  const int l15 = lane & 15, l4 = lane >> 4;
  const size_t bT = (size_t)b * kT;
  const int sA = l15 + 32 * (l4 & 1);
  const int sB = sA + 16;
  const bool hi = l4 >= 2;
  const int srow = tid >> 3, sc8 = (tid & 7) * 8;
  const int sidx = (srow * 64 + sc8) ^ ((srow & 7) << 3);

  const int tw = t0 + 16 * w;       // wave's first t-row
  const u16* qp = qb + (bT + tw + l15) * 64 + 8 * l4;
  const bf16x8 qf0 = *reinterpret_cast<const bf16x8*>(qp);
  const bf16x8 qf1 = *reinterpret_cast<const bf16x8*>(qp + 32);

  f32x4 acc[4];
#pragma unroll
  for (int nf = 0; nf < 4; ++nf) acc[nf] = f32x4{0.f, 0.f, 0.f, 0.f};

  const int js0 = q4 * 8;
  const int js1 = min(js0 + 8, 2 * tt + 2);
  for (int js = js0; js < js1; ++js) {
    const int s0 = js * 64;
    __syncthreads();  // previous iteration done reading LDS
    *reinterpret_cast<uint4*>(&kl[sidx]) =
        *reinterpret_cast<const uint4*>(&kb[(bT + s0 + srow) * 64 + sc8]);
    *reinterpret_cast<uint4*>(&vl[sidx]) =
        *reinterpret_cast<const uint4*>(&vt[(size_t)(b * 64 + srow) * kT + s0 + sc8]);
    __syncthreads();  // stage visible
    if (tw + 15 < s0) continue;  // wave entirely below this s-tile

    // per-lane 1/l for rows s = s0+16jf+4l4+r (issued early)
    float4 lv[4];
#pragma unroll
    for (int jf = 0; jf < 4; ++jf)
      lv[jf] = *reinterpret_cast<const float4*>(&lG[bT + s0 + 16 * jf + 4 * l4]);

    // QK^T (swapped): kf from LDS; D[s][t], row s = s0+16jf+4l4+r, col t = tw+l15
    unsigned pk0[4], pk1[4];
    const int t = tw + l15;
    const bool masked = (s0 + 63 > tw);  // wave-uniform
#pragma unroll
    for (int jf = 0; jf < 4; ++jf) {
      const int krow = 16 * jf + l15;
      const bf16x8 kf0 = *reinterpret_cast<const bf16x8*>(
          &kl[(krow * 64 + 8 * l4) ^ ((krow & 7) << 3)]);
      const bf16x8 kf1 = *reinterpret_cast<const bf16x8*>(
          &kl[(krow * 64 + 32 + 8 * l4) ^ ((krow & 7) << 3)]);
      f32x4 d = f32x4{0.f, 0.f, 0.f, 0.f};
      d = mfma16(kf0, qf0, d);
      d = mfma16(kf1, qf1, d);
      const float rl0 = __builtin_amdgcn_rcpf(lv[jf].x);
      const float rl1 = __builtin_amdgcn_rcpf(lv[jf].y);
      const float rl2 = __builtin_amdgcn_rcpf(lv[jf].z);
      const float rl3 = __builtin_amdgcn_rcpf(lv[jf].w);
      float p[4];
      if (masked) {
        const int sb = s0 + 16 * jf + 4 * l4;
        p[0] = (t >= sb + 0) ? __expf(d[0] * kScale) * rl0 : 0.f;
        p[1] = (t >= sb + 1) ? __expf(d[1] * kScale) * rl1 : 0.f;
        p[2] = (t >= sb + 2) ? __expf(d[2] * kScale) * rl2 : 0.f;
        p[3] = (t >= sb + 3) ? __expf(d[3] * kScale) * rl3 : 0.f;
      } else {
        p[0] = __expf(d[0] * kScale) * rl0;
        p[1] = __expf(d[1] * kScale) * rl1;
        p[2] = __expf(d[2] * kScale) * rl2;
        p[3] = __expf(d[3] * kScale) * rl3;
      }
      pk0[jf] = (unsigned)f2bu(p[0]) | ((unsigned)f2bu(p[1]) << 16);
      pk1[jf] = (unsigned)f2bu(p[2]) | ((unsigned)f2bu(p[3]) << 16);
    }
    // chunk 0 (s_loc 0..31): shuffle-transpose + PV from LDS v^T
    {
      const unsigned a0 = __shfl(pk0[0], sA), a1 = __shfl(pk1[0], sA);
      const unsigned a2 = __shfl(pk0[0], sB), a3 = __shfl(pk1[0], sB);
      const unsigned b0 = __shfl(pk0[1], sA), b1 = __shfl(pk1[1], sA);
      const unsigned b2 = __shfl(pk0[1], sB), b3 = __shfl(pk1[1], sB);
      uint4 pw;
      pw.x = hi ? b0 : a0; pw.y = hi ? b1 : a1;
      pw.z = hi ? b2 : a2; pw.w = hi ? b3 : a3;
      const bf16x8 pa = *reinterpret_cast<const bf16x8*>(&pw);
#pragma unroll
      for (int nf = 0; nf < 4; ++nf) {
        const int vrow = 16 * nf + l15;
        const bf16x8 vf = *reinterpret_cast<const bf16x8*>(
            &vl[(vrow * 64 + 8 * l4) ^ ((vrow & 7) << 3)]);
        acc[nf] = mfma16(pa, vf, acc[nf]);
      }
    }
    // chunk 1 (s_loc 32..63)
    {
      const unsigned a0 = __shfl(pk0[2], sA), a1 = __shfl(pk1[2], sA);
      const unsigned a2 = __shfl(pk0[2], sB), a3 = __shfl(pk1[2], sB);
      const unsigned b0 = __shfl(pk0[3], sA), b1 = __shfl(pk1[3], sA);
      const unsigned b2 = __shfl(pk0[3], sB), b3 = __shfl(pk1[3], sB);
      uint4 pw;
      pw.x = hi ? b0 : a0; pw.y = hi ? b1 : a1;
      pw.z = hi ? b2 : a2; pw.w = hi ? b3 : a3;
      const bf16x8 pa = *reinterpret_cast<const bf16x8*>(&pw);
#pragma unroll
      for (int nf = 0; nf < 4; ++nf) {
        const int vrow = 16 * nf + l15;
        const bf16x8 vf = *reinterpret_cast<const bf16x8*>(
            &vl[(vrow * 64 + 32 + 8 * l4) ^ ((vrow & 7) << 3)]);
        acc[nf] = mfma16(pa, vf, acc[nf]);
      }
    }
  }
  // write partial tile (unconditional; zero if no work)
  float* pb = part + (size_t)(q4 * 8 + b) * kT * kH;
#pragma unroll
  for (int nf = 0; nf < 4; ++nf) {
#pragma unroll
    for (int r = 0; r < 4; ++r) {
      pb[(size_t)(tw + 4 * l4 + r) * 64 + 16 * nf + l15] = acc[nf][r];
    }
  }
}

// K3b: out = part0 + part1 + part2 + part3 (fixed order -> deterministic)
__global__ __launch_bounds__(256) void combine_kernel(
    const float* __restrict__ part, float* __restrict__ out) {
  const size_t i = ((size_t)blockIdx.x * 256 + threadIdx.x) * 4;
  const float4 p0 = *reinterpret_cast<const float4*>(part + i);
  const float4 p1 = *reinterpret_cast<const float4*>(part + 1048576 + i);
  const float4 p2 = *reinterpret_cast<const float4*>(part + 2097152 + i);
  const float4 p3 = *reinterpret_cast<const float4*>(part + 3145728 + i);
  float4 s;
  s.x = p0.x + p1.x + p2.x + p3.x;
  s.y = p0.y + p1.y + p2.y + p3.y;
  s.z = p0.z + p1.z + p2.z + p3.z;
  s.w = p0.w + p1.w + p2.w + p3.w;
  *reinterpret_cast<float4*>(out + i) = s;
}

}  // namespace

extern "C" void kernel_launch(void* const* d_in, const int* in_sizes, int n_in,
                              void* d_out, int out_size, void* d_ws, size_t ws_size,
                              hipStream_t stream) {
  const float* x = (const float*)d_in[0];
  const float* Wk = (const float*)d_in[1];
  const float* Wq = (const float*)d_in[2];
  const float* Wv = (const float*)d_in[3];
  u16* wsu = (u16*)d_ws;
  u16* Wt = wsu + kWtOff;
  u16* qb = wsu + kQbOff;
  u16* kb = wsu + kKbOff;
  u16* vt = wsu + kVtOff;
  float* lG = (float*)(wsu + kLOff);
  float* part = (float*)(wsu + kPartOff);
  float* out = (float*)d_out;

  zero_l_kernel<<<dim3(kB * kT / 256), dim3(256), 0, stream>>>(lG);
  wt_kernel<<<dim3(16, 3), dim3(256), 0, stream>>>(Wk, Wq, Wv, Wt);
  qkv_kernel<<<dim3(kB * kT / 64), dim3(512), 0, stream>>>(x, Wt, qb, kb, vt);
  colsum_kernel<<<dim3(1024), dim3(256), 0, stream>>>(qb, kb, lG);
  out_part_kernel<<<dim3(512), dim3(512), 0, stream>>>(qb, kb, vt, lG, part);
  combine_kernel<<<dim3(1024), dim3(256), 0, stream>>>(part, out);
}

// Round 23
// 74.468 us; speedup vs baseline: 1.2408x; 1.2408x over previous
//
#include <hip/hip_runtime.h>
#include <hip/hip_bf16.h>

namespace {

typedef unsigned short u16;
typedef __attribute__((ext_vector_type(8))) short bf16x8;
typedef __attribute__((ext_vector_type(4))) float f32x4;

constexpr int kB = 8, kT = 2048, kC = 1024, kH = 64;
constexpr float kScale = 0.03125f;  // 1024^-0.5

// workspace layout in u16 elements
constexpr size_t kWtOff = 0;                                 // 3*64*1024
constexpr size_t kQbOff = kWtOff + 3 * 64 * 1024;            // 16384*64
constexpr size_t kKbOff = kQbOff + (size_t)16384 * 64;
constexpr size_t kVtOff = kKbOff + (size_t)16384 * 64;       // v^T [b*64+h][t]
constexpr size_t kLOff  = kVtOff + (size_t)16384 * 64;       // float l[16384]
constexpr size_t kPartOff = kLOff + (size_t)16384 * 2;       // float part[4][1M]

__device__ __forceinline__ u16 f2bu(float f) {
  __hip_bfloat16 h = __float2bfloat16(f);
  return *reinterpret_cast<u16*>(&h);
}
__device__ __forceinline__ f32x4 mfma16(bf16x8 a, bf16x8 b, f32x4 c) {
  return __builtin_amdgcn_mfma_f32_16x16x32_bf16(a, b, c, 0, 0, 0);
}

__global__ __launch_bounds__(256) void zero_l_kernel(float* __restrict__ l) {
  l[blockIdx.x * 256 + threadIdx.x] = 0.f;
}

// K0: Wt[mat][h][c] = bf16(W[c][h])  (rows indexed by ncol = mat*64+h)
__global__ __launch_bounds__(256) void wt_kernel(
    const float* __restrict__ Wk, const float* __restrict__ Wq,
    const float* __restrict__ Wv, u16* __restrict__ Wt) {
  __shared__ float wsm[64 * 65];
  const int c0 = blockIdx.x * 64;
  const int mat = blockIdx.y;
  const float* W = (mat == 0) ? Wk : (mat == 1) ? Wq : Wv;
  const int tid = threadIdx.x;
#pragma unroll
  for (int ii = 0; ii < 4; ++ii) {
    const int p = tid + 256 * ii;
    const int row = p >> 4, col4 = p & 15;
    const float4 wv = *reinterpret_cast<const float4*>(&W[(size_t)(c0 + row) * 64 + col4 * 4]);
    wsm[row * 65 + col4 * 4 + 0] = wv.x;
    wsm[row * 65 + col4 * 4 + 1] = wv.y;
    wsm[row * 65 + col4 * 4 + 2] = wv.z;
    wsm[row * 65 + col4 * 4 + 3] = wv.w;
  }
  __syncthreads();
  const int h = tid & 63, seg = tid >> 6;
#pragma unroll
  for (int i = 0; i < 16; ++i) {
    const int c = seg * 16 + i;
    Wt[((size_t)mat * 64 + h) * 1024 + c0 + c] = f2bu(wsm[c * 65 + h]);
  }
}

// K1: fused q,k,v GEMM.  BM=32 (512 blocks = 2/CU), 4 waves, 8 K-phases of 128.
// Per phase: cooperative bulk-fill of W[192][128] + x[32][128] into swizzled
// LDS, then pure-LDS MFMA (24/wave).  Wave w owns N-cols [48w, 48w+48).
// NOTE: BM sweep measured {16: 40us, 32: 30us, 64: 45us} -> BM=32 optimal
// (cross-block fill/compute overlap at 2/CU beats both more-TLP and less-fill).
__global__ __launch_bounds__(256) void qkv_kernel(
    const float* __restrict__ x, const u16* __restrict__ Wt,
    u16* __restrict__ qb, u16* __restrict__ kb, u16* __restrict__ vt) {
  __shared__ u16 wl[192 * 128];  // 48 KiB, XOR-swizzled (u16-idx bits 3-5 ^ row&7)
  __shared__ u16 xl[32 * 128];   // 8 KiB, same swizzle
  const int tid = threadIdx.x;
  const int lane = tid & 63, w = tid >> 6;
  const int l15 = lane & 15, l4 = lane >> 4;
  const int m0 = blockIdx.x * 32;

  f32x4 acc[2][3];
#pragma unroll
  for (int mi = 0; mi < 2; ++mi)
#pragma unroll
    for (int ni = 0; ni < 3; ++ni) acc[mi][ni] = f32x4{0.f, 0.f, 0.f, 0.f};

  for (int p = 0; p < 8; ++p) {
    const int k0 = p * 128;
    __syncthreads();
#pragma unroll
    for (int i = 0; i < 12; ++i) {
      const int q = tid + 256 * i;
      const int row = q >> 4, c8 = (q & 15) * 8;
      const uint4 wv = *reinterpret_cast<const uint4*>(&Wt[(size_t)row * 1024 + k0 + c8]);
      *reinterpret_cast<uint4*>(&wl[(row * 128 + c8) ^ ((row & 7) << 3)]) = wv;
    }
#pragma unroll
    for (int i = 0; i < 4; ++i) {
      const int q = tid + 256 * i;
      const int row = q >> 5, c4 = (q & 31) * 4;
      const float4 xv = *reinterpret_cast<const float4*>(&x[(size_t)(m0 + row) * kC + k0 + c4]);
      uint2 pk;
      pk.x = (unsigned)f2bu(xv.x) | ((unsigned)f2bu(xv.y) << 16);
      pk.y = (unsigned)f2bu(xv.z) | ((unsigned)f2bu(xv.w) << 16);
      *reinterpret_cast<uint2*>(&xl[(row * 128 + c4) ^ ((row & 7) << 3)]) = pk;
    }
    __syncthreads();
#pragma unroll
    for (int ks = 0; ks < 4; ++ks) {
      const int kk = ks * 32 + 8 * l4;
      bf16x8 a[2];
#pragma unroll
      for (int mi = 0; mi < 2; ++mi) {
        const int row = 16 * mi + l15;
        a[mi] = *reinterpret_cast<const bf16x8*>(&xl[(row * 128 + kk) ^ ((row & 7) << 3)]);
      }
#pragma unroll
      for (int ni = 0; ni < 3; ++ni) {
        const int row = 48 * w + 16 * ni + l15;
        const bf16x8 bfr =
            *reinterpret_cast<const bf16x8*>(&wl[(row * 128 + kk) ^ ((row & 7) << 3)]);
#pragma unroll
        for (int mi = 0; mi < 2; ++mi) acc[mi][ni] = mfma16(a[mi], bfr, acc[mi][ni]);
      }
    }
  }
#pragma unroll
  for (int ni = 0; ni < 3; ++ni) {
    const int ncol = 48 * w + 16 * ni + l15;
    const int mat = ncol >> 6, h = ncol & 63;
#pragma unroll
    for (int mi = 0; mi < 2; ++mi) {
#pragma unroll
      for (int r = 0; r < 4; ++r) {
        const int m = m0 + 16 * mi + 4 * l4 + r;
        const u16 val = f2bu(acc[mi][ni][r]);
        if (mat == 0) kb[(size_t)m * 64 + h] = val;
        else if (mat == 1) qb[(size_t)m * 64 + h] = val;
        else vt[((size_t)((m >> 11) * 64 + h)) * 2048 + (m & 2047)] = val;
      }
    }
  }
}

// K2: l[b,s] = sum_{t>=s} exp(scale * q_t.k_s).  mfma(A=K, B=Q) -> D[s][t].
__global__ __launch_bounds__(256) void colsum_kernel(
    const u16* __restrict__ qb, const u16* __restrict__ kb, float* __restrict__ lG) {
  const int bid = blockIdx.x;
  const int b = bid & 7;
  const int rr = bid >> 3;
  const int s0 = (rr & 31) * 64;
  const int tc = (rr >> 5) * 512;
  if (tc + 511 < s0) return;
  const int tid = threadIdx.x;
  const int lane = tid & 63, w = tid >> 6;
  const int l15 = lane & 15, l4 = lane >> 4;

  bf16x8 ka[4][2];
#pragma unroll
  for (int i = 0; i < 4; ++i) {
    const u16* kp = kb + (size_t)(b * kT + s0 + 16 * i + l15) * 64 + 8 * l4;
    ka[i][0] = *reinterpret_cast<const bf16x8*>(kp);
    ka[i][1] = *reinterpret_cast<const bf16x8*>(kp + 32);
  }
  f32x4 cs[4];
#pragma unroll
  for (int i = 0; i < 4; ++i) cs[i] = f32x4{0.f, 0.f, 0.f, 0.f};

  const int d0 = s0 - tc - 128 * w;
  const int jstart = (d0 > 0) ? (d0 >> 4) : 0;
  const u16* qbase = qb + (size_t)(b * kT + tc + 128 * w + l15) * 64 + 8 * l4;
  bf16x8 qf0, qf1;
  if (jstart < 8) {
    qf0 = *reinterpret_cast<const bf16x8*>(qbase + (size_t)jstart * 1024);
    qf1 = *reinterpret_cast<const bf16x8*>(qbase + (size_t)jstart * 1024 + 32);
  }
  for (int j = jstart; j < 8; ++j) {
    bf16x8 qn0, qn1;
    if (j < 7) {
      qn0 = *reinterpret_cast<const bf16x8*>(qbase + (size_t)(j + 1) * 1024);
      qn1 = *reinterpret_cast<const bf16x8*>(qbase + (size_t)(j + 1) * 1024 + 32);
    }
    const int t = tc + 128 * w + 16 * j + l15;
#pragma unroll
    for (int i = 0; i < 4; ++i) {
      f32x4 d = f32x4{0.f, 0.f, 0.f, 0.f};
      d = mfma16(ka[i][0], qf0, d);
      d = mfma16(ka[i][1], qf1, d);
#pragma unroll
      for (int r = 0; r < 4; ++r) {
        const int s = s0 + 16 * i + 4 * l4 + r;
        if (t >= s) cs[i][r] += __expf(d[r] * kScale);
      }
    }
    qf0 = qn0; qf1 = qn1;
  }
#pragma unroll
  for (int i = 0; i < 4; ++i) {
#pragma unroll
    for (int r = 0; r < 4; ++r) {
      float v = cs[i][r];
      v += __shfl_xor(v, 1, 64);
      v += __shfl_xor(v, 2, 64);
      v += __shfl_xor(v, 4, 64);
      v += __shfl_xor(v, 8, 64);
      if (l15 == 0) atomicAdd(&lG[b * kT + s0 + 16 * i + 4 * l4 + r], v);
    }
  }
}

// K3a: partial PV over one s-quarter.  Block = (b, 128-row t-tile tt, quarter
// q4): 512 blocks x 8 waves.  Per s-tile of 64: cooperative LDS stage of
// k[64][64] + v^T[64][64], swapped QK^T -> (exp * rcp(l)) -> shuffle
// transpose -> PV.  1/l folded here (no vscale pass).  part[q4][b][t][h].
__global__ __launch_bounds__(512, 4) void out_part_kernel(
    const u16* __restrict__ qb, const u16* __restrict__ kb, const u16* __restrict__ vt,
    const float* __restrict__ lG, float* __restrict__ part) {
  __shared__ u16 kl[64 * 64];  // 8 KiB, XOR-swizzled
  __shared__ u16 vl[64 * 64];  // 8 KiB, XOR-swizzled
  const int bid = blockIdx.x;
  const int b = bid & 7;            // batch-per-XCD L2 locality
  const int q4 = (bid >> 3) & 3;    // s-quarter
  const int tt = bid >> 5;          // 0..15
  const int t0 = tt * 128;
  const int tid = threadIdx.x;
  const int lane = tid & 63, w = tid >> 6;
  const int l15 = lane & 15, l4 = lane >> 4;
  const size_t bT = (size_t)b * kT;
  const int sA = l15 + 32 * (l4 & 1);
  const int sB = sA + 16;
  const bool hi = l4 >= 2;
  const int srow = tid >> 3, sc8 = (tid & 7) * 8;
  const int sidx = (srow * 64 + sc8) ^ ((srow & 7) << 3);

  const int tw = t0 + 16 * w;       // wave's first t-row
  const u16* qp = qb + (bT + tw + l15) * 64 + 8 * l4;
  const bf16x8 qf0 = *reinterpret_cast<const bf16x8*>(qp);
  const bf16x8 qf1 = *reinterpret_cast<const bf16x8*>(qp + 32);

  f32x4 acc[4];
#pragma unroll
  for (int nf = 0; nf < 4; ++nf) acc[nf] = f32x4{0.f, 0.f, 0.f, 0.f};

  const int js0 = q4 * 8;
  const int js1 = min(js0 + 8, 2 * tt + 2);
  for (int js = js0; js < js1; ++js) {
    const int s0 = js * 64;
    __syncthreads();  // previous iteration done reading LDS
    *reinterpret_cast<uint4*>(&kl[sidx]) =
        *reinterpret_cast<const uint4*>(&kb[(bT + s0 + srow) * 64 + sc8]);
    *reinterpret_cast<uint4*>(&vl[sidx]) =
        *reinterpret_cast<const uint4*>(&vt[(size_t)(b * 64 + srow) * kT + s0 + sc8]);
    __syncthreads();  // stage visible
    if (tw + 15 < s0) continue;  // wave entirely below this s-tile

    // per-lane 1/l for rows s = s0+16jf+4l4+r (issued early)
    float4 lv[4];
#pragma unroll
    for (int jf = 0; jf < 4; ++jf)
      lv[jf] = *reinterpret_cast<const float4*>(&lG[bT + s0 + 16 * jf + 4 * l4]);

    // QK^T (swapped): kf from LDS; D[s][t], row s = s0+16jf+4l4+r, col t = tw+l15
    unsigned pk0[4], pk1[4];
    const int t = tw + l15;
    const bool masked = (s0 + 63 > tw);  // wave-uniform
#pragma unroll
    for (int jf = 0; jf < 4; ++jf) {
      const int krow = 16 * jf + l15;
      const bf16x8 kf0 = *reinterpret_cast<const bf16x8*>(
          &kl[(krow * 64 + 8 * l4) ^ ((krow & 7) << 3)]);
      const bf16x8 kf1 = *reinterpret_cast<const bf16x8*>(
          &kl[(krow * 64 + 32 + 8 * l4) ^ ((krow & 7) << 3)]);
      f32x4 d = f32x4{0.f, 0.f, 0.f, 0.f};
      d = mfma16(kf0, qf0, d);
      d = mfma16(kf1, qf1, d);
      const float rl0 = __builtin_amdgcn_rcpf(lv[jf].x);
      const float rl1 = __builtin_amdgcn_rcpf(lv[jf].y);
      const float rl2 = __builtin_amdgcn_rcpf(lv[jf].z);
      const float rl3 = __builtin_amdgcn_rcpf(lv[jf].w);
      float p[4];
      if (masked) {
        const int sb = s0 + 16 * jf + 4 * l4;
        p[0] = (t >= sb + 0) ? __expf(d[0] * kScale) * rl0 : 0.f;
        p[1] = (t >= sb + 1) ? __expf(d[1] * kScale) * rl1 : 0.f;
        p[2] = (t >= sb + 2) ? __expf(d[2] * kScale) * rl2 : 0.f;
        p[3] = (t >= sb + 3) ? __expf(d[3] * kScale) * rl3 : 0.f;
      } else {
        p[0] = __expf(d[0] * kScale) * rl0;
        p[1] = __expf(d[1] * kScale) * rl1;
        p[2] = __expf(d[2] * kScale) * rl2;
        p[3] = __expf(d[3] * kScale) * rl3;
      }
      pk0[jf] = (unsigned)f2bu(p[0]) | ((unsigned)f2bu(p[1]) << 16);
      pk1[jf] = (unsigned)f2bu(p[2]) | ((unsigned)f2bu(p[3]) << 16);
    }
    // chunk 0 (s_loc 0..31): shuffle-transpose + PV from LDS v^T
    {
      const unsigned a0 = __shfl(pk0[0], sA), a1 = __shfl(pk1[0], sA);
      const unsigned a2 = __shfl(pk0[0], sB), a3 = __shfl(pk1[0], sB);
      const unsigned b0 = __shfl(pk0[1], sA), b1 = __shfl(pk1[1], sA);
      const unsigned b2 = __shfl(pk0[1], sB), b3 = __shfl(pk1[1], sB);
      uint4 pw;
      pw.x = hi ? b0 : a0; pw.y = hi ? b1 : a1;
      pw.z = hi ? b2 : a2; pw.w = hi ? b3 : a3;
      const bf16x8 pa = *reinterpret_cast<const bf16x8*>(&pw);
#pragma unroll
      for (int nf = 0; nf < 4; ++nf) {
        const int vrow = 16 * nf + l15;
        const bf16x8 vf = *reinterpret_cast<const bf16x8*>(
            &vl[(vrow * 64 + 8 * l4) ^ ((vrow & 7) << 3)]);
        acc[nf] = mfma16(pa, vf, acc[nf]);
      }
    }
    // chunk 1 (s_loc 32..63)
    {
      const unsigned a0 = __shfl(pk0[2], sA), a1 = __shfl(pk1[2], sA);
      const unsigned a2 = __shfl(pk0[2], sB), a3 = __shfl(pk1[2], sB);
      const unsigned b0 = __shfl(pk0[3], sA), b1 = __shfl(pk1[3], sA);
      const unsigned b2 = __shfl(pk0[3], sB), b3 = __shfl(pk1[3], sB);
      uint4 pw;
      pw.x = hi ? b0 : a0; pw.y = hi ? b1 : a1;
      pw.z = hi ? b2 : a2; pw.w = hi ? b3 : a3;
      const bf16x8 pa = *reinterpret_cast<const bf16x8*>(&pw);
#pragma unroll
      for (int nf = 0; nf < 4; ++nf) {
        const int vrow = 16 * nf + l15;
        const bf16x8 vf = *reinterpret_cast<const bf16x8*>(
            &vl[(vrow * 64 + 32 + 8 * l4) ^ ((vrow & 7) << 3)]);
        acc[nf] = mfma16(pa, vf, acc[nf]);
      }
    }
  }
  // write partial tile (unconditional; zero if no work)
  float* pb = part + (size_t)(q4 * 8 + b) * kT * kH;
#pragma unroll
  for (int nf = 0; nf < 4; ++nf) {
#pragma unroll
    for (int r = 0; r < 4; ++r) {
      pb[(size_t)(tw + 4 * l4 + r) * 64 + 16 * nf + l15] = acc[nf][r];
    }
  }
}

// K3b: out = part0 + part1 + part2 + part3 (fixed order -> deterministic)
__global__ __launch_bounds__(256) void combine_kernel(
    const float* __restrict__ part, float* __restrict__ out) {
  const size_t i = ((size_t)blockIdx.x * 256 + threadIdx.x) * 4;
  const float4 p0 = *reinterpret_cast<const float4*>(part + i);
  const float4 p1 = *reinterpret_cast<const float4*>(part + 1048576 + i);
  const float4 p2 = *reinterpret_cast<const float4*>(part + 2097152 + i);
  const float4 p3 = *reinterpret_cast<const float4*>(part + 3145728 + i);
  float4 s;
  s.x = p0.x + p1.x + p2.x + p3.x;
  s.y = p0.y + p1.y + p2.y + p3.y;
  s.z = p0.z + p1.z + p2.z + p3.z;
  s.w = p0.w + p1.w + p2.w + p3.w;
  *reinterpret_cast<float4*>(out + i) = s;
}

}  // namespace

extern "C" void kernel_launch(void* const* d_in, const int* in_sizes, int n_in,
                              void* d_out, int out_size, void* d_ws, size_t ws_size,
                              hipStream_t stream) {
  const float* x = (const float*)d_in[0];
  const float* Wk = (const float*)d_in[1];
  const float* Wq = (const float*)d_in[2];
  const float* Wv = (const float*)d_in[3];
  u16* wsu = (u16*)d_ws;
  u16* Wt = wsu + kWtOff;
  u16* qb = wsu + kQbOff;
  u16* kb = wsu + kKbOff;
  u16* vt = wsu + kVtOff;
  float* lG = (float*)(wsu + kLOff);
  float* part = (float*)(wsu + kPartOff);
  float* out = (float*)d_out;

  zero_l_kernel<<<dim3(kB * kT / 256), dim3(256), 0, stream>>>(lG);
  wt_kernel<<<dim3(16, 3), dim3(256), 0, stream>>>(Wk, Wq, Wv, Wt);
  qkv_kernel<<<dim3(kB * kT / 32), dim3(256), 0, stream>>>(x, Wt, qb, kb, vt);
  colsum_kernel<<<dim3(1024), dim3(256), 0, stream>>>(qb, kb, lG);
  out_part_kernel<<<dim3(512), dim3(512), 0, stream>>>(qb, kb, vt, lG, part);
  combine_kernel<<<dim3(1024), dim3(256), 0, stream>>>(part, out);
}

// Round 24
// 66.260 us; speedup vs baseline: 1.3945x; 1.1239x over previous
//
#include <hip/hip_runtime.h>
#include <hip/hip_bf16.h>

namespace {

typedef unsigned short u16;
typedef __attribute__((ext_vector_type(8))) short bf16x8;
typedef __attribute__((ext_vector_type(4))) float f32x4;

constexpr int kB = 8, kT = 2048, kC = 1024, kH = 64;
constexpr float kScale = 0.03125f;  // 1024^-0.5

// workspace layout in u16 elements
constexpr size_t kWtOff = 0;                                 // 3*64*1024
constexpr size_t kQbOff = kWtOff + 3 * 64 * 1024;            // 16384*64
constexpr size_t kKbOff = kQbOff + (size_t)16384 * 64;
constexpr size_t kVtOff = kKbOff + (size_t)16384 * 64;       // v^T [b*64+h][t]
constexpr size_t kLOff  = kVtOff + (size_t)16384 * 64;       // float l[16384]
constexpr size_t kPartOff = kLOff + (size_t)16384 * 2;       // float part[4][1M]
constexpr size_t kLPartOff = kPartOff + (size_t)4 * 1048576 * 2;  // float lpart[4][16384]

__device__ __forceinline__ u16 f2bu(float f) {
  __hip_bfloat16 h = __float2bfloat16(f);
  return *reinterpret_cast<u16*>(&h);
}
__device__ __forceinline__ f32x4 mfma16(bf16x8 a, bf16x8 b, f32x4 c) {
  return __builtin_amdgcn_mfma_f32_16x16x32_bf16(a, b, c, 0, 0, 0);
}

// K0: Wt[mat][h][c] = bf16(W[c][h])  (rows indexed by ncol = mat*64+h)
__global__ __launch_bounds__(256) void wt_kernel(
    const float* __restrict__ Wk, const float* __restrict__ Wq,
    const float* __restrict__ Wv, u16* __restrict__ Wt) {
  __shared__ float wsm[64 * 65];
  const int c0 = blockIdx.x * 64;
  const int mat = blockIdx.y;
  const float* W = (mat == 0) ? Wk : (mat == 1) ? Wq : Wv;
  const int tid = threadIdx.x;
#pragma unroll
  for (int ii = 0; ii < 4; ++ii) {
    const int p = tid + 256 * ii;
    const int row = p >> 4, col4 = p & 15;
    const float4 wv = *reinterpret_cast<const float4*>(&W[(size_t)(c0 + row) * 64 + col4 * 4]);
    wsm[row * 65 + col4 * 4 + 0] = wv.x;
    wsm[row * 65 + col4 * 4 + 1] = wv.y;
    wsm[row * 65 + col4 * 4 + 2] = wv.z;
    wsm[row * 65 + col4 * 4 + 3] = wv.w;
  }
  __syncthreads();
  const int h = tid & 63, seg = tid >> 6;
#pragma unroll
  for (int i = 0; i < 16; ++i) {
    const int c = seg * 16 + i;
    Wt[((size_t)mat * 64 + h) * 1024 + c0 + c] = f2bu(wsm[c * 65 + h]);
  }
}

// K1: fused q,k,v GEMM.  BM=32 (512 blocks = 2/CU), 4 waves, 8 K-phases of 128.
// NOTE: BM sweep measured {16: 40us, 32: 30us, 64: 45us} -> BM=32 optimal.
__global__ __launch_bounds__(256) void qkv_kernel(
    const float* __restrict__ x, const u16* __restrict__ Wt,
    u16* __restrict__ qb, u16* __restrict__ kb, u16* __restrict__ vt) {
  __shared__ u16 wl[192 * 128];  // 48 KiB, XOR-swizzled (u16-idx bits 3-5 ^ row&7)
  __shared__ u16 xl[32 * 128];   // 8 KiB, same swizzle
  const int tid = threadIdx.x;
  const int lane = tid & 63, w = tid >> 6;
  const int l15 = lane & 15, l4 = lane >> 4;
  const int m0 = blockIdx.x * 32;

  f32x4 acc[2][3];
#pragma unroll
  for (int mi = 0; mi < 2; ++mi)
#pragma unroll
    for (int ni = 0; ni < 3; ++ni) acc[mi][ni] = f32x4{0.f, 0.f, 0.f, 0.f};

  for (int p = 0; p < 8; ++p) {
    const int k0 = p * 128;
    __syncthreads();
#pragma unroll
    for (int i = 0; i < 12; ++i) {
      const int q = tid + 256 * i;
      const int row = q >> 4, c8 = (q & 15) * 8;
      const uint4 wv = *reinterpret_cast<const uint4*>(&Wt[(size_t)row * 1024 + k0 + c8]);
      *reinterpret_cast<uint4*>(&wl[(row * 128 + c8) ^ ((row & 7) << 3)]) = wv;
    }
#pragma unroll
    for (int i = 0; i < 4; ++i) {
      const int q = tid + 256 * i;
      const int row = q >> 5, c4 = (q & 31) * 4;
      const float4 xv = *reinterpret_cast<const float4*>(&x[(size_t)(m0 + row) * kC + k0 + c4]);
      uint2 pk;
      pk.x = (unsigned)f2bu(xv.x) | ((unsigned)f2bu(xv.y) << 16);
      pk.y = (unsigned)f2bu(xv.z) | ((unsigned)f2bu(xv.w) << 16);
      *reinterpret_cast<uint2*>(&xl[(row * 128 + c4) ^ ((row & 7) << 3)]) = pk;
    }
    __syncthreads();
#pragma unroll
    for (int ks = 0; ks < 4; ++ks) {
      const int kk = ks * 32 + 8 * l4;
      bf16x8 a[2];
#pragma unroll
      for (int mi = 0; mi < 2; ++mi) {
        const int row = 16 * mi + l15;
        a[mi] = *reinterpret_cast<const bf16x8*>(&xl[(row * 128 + kk) ^ ((row & 7) << 3)]);
      }
#pragma unroll
      for (int ni = 0; ni < 3; ++ni) {
        const int row = 48 * w + 16 * ni + l15;
        const bf16x8 bfr =
            *reinterpret_cast<const bf16x8*>(&wl[(row * 128 + kk) ^ ((row & 7) << 3)]);
#pragma unroll
        for (int mi = 0; mi < 2; ++mi) acc[mi][ni] = mfma16(a[mi], bfr, acc[mi][ni]);
      }
    }
  }
#pragma unroll
  for (int ni = 0; ni < 3; ++ni) {
    const int ncol = 48 * w + 16 * ni + l15;
    const int mat = ncol >> 6, h = ncol & 63;
#pragma unroll
    for (int mi = 0; mi < 2; ++mi) {
#pragma unroll
      for (int r = 0; r < 4; ++r) {
        const int m = m0 + 16 * mi + 4 * l4 + r;
        const u16 val = f2bu(acc[mi][ni][r]);
        if (mat == 0) kb[(size_t)m * 64 + h] = val;
        else if (mat == 1) qb[(size_t)m * 64 + h] = val;
        else vt[((size_t)((m >> 11) * 64 + h)) * 2048 + (m & 2047)] = val;
      }
    }
  }
}

// K2a: partial col-sum over one t-quarter (mirror of out_part pattern).
// Block = (b, 128-row s-tile ss, t-quarter q4): 512 blocks x 8 waves,
// 8 KB LDS -> 4 blocks/CU.  Wave owns 16 s-rows (K in regs, loaded once);
// per 64-wide t-tile: cooperative LDS stage of q[64][64] shared by all
// waves, mfma(K,Q) -> D[s][t], masked exp only on boundary tiles, lane-tree
// reduce over t.  No atomics: lpart[q4][b*kT + s].
__global__ __launch_bounds__(512) void colsum_part_kernel(
    const u16* __restrict__ qb, const u16* __restrict__ kb, float* __restrict__ lpart) {
  __shared__ u16 ql[64 * 64];  // 8 KiB, XOR-swizzled
  const int bid = blockIdx.x;
  const int b = bid & 7;            // batch-per-XCD L2 locality
  const int q4 = (bid >> 3) & 3;    // t-quarter
  const int ss = bid >> 5;          // 0..15 (128-row s-tile)
  const int tid = threadIdx.x;
  const int lane = tid & 63, w = tid >> 6;
  const int l15 = lane & 15, l4 = lane >> 4;
  const size_t bT = (size_t)b * kT;
  const int srow = tid >> 3, sc8 = (tid & 7) * 8;
  const int sidx = (srow * 64 + sc8) ^ ((srow & 7) << 3);

  const int sw = ss * 128 + 16 * w;  // wave's first s-row
  const u16* kp = kb + (bT + sw + l15) * 64 + 8 * l4;
  const bf16x8 ka0 = *reinterpret_cast<const bf16x8*>(kp);
  const bf16x8 ka1 = *reinterpret_cast<const bf16x8*>(kp + 32);

  float cs[4] = {0.f, 0.f, 0.f, 0.f};

  const int jt0 = max(q4 * 8, 2 * ss);
  const int jt1 = q4 * 8 + 8;
  for (int jt = jt0; jt < jt1; ++jt) {
    const int t0 = jt * 64;
    __syncthreads();  // previous tile done reading LDS
    *reinterpret_cast<uint4*>(&ql[sidx]) =
        *reinterpret_cast<const uint4*>(&qb[(bT + t0 + srow) * 64 + sc8]);
    __syncthreads();  // stage visible
    const bool masked = (t0 < sw + 15);  // wave-uniform
#pragma unroll
    for (int c = 0; c < 4; ++c) {
      const int tl = 16 * c + l15;
      const bf16x8 qf0 = *reinterpret_cast<const bf16x8*>(
          &ql[(tl * 64 + 8 * l4) ^ ((tl & 7) << 3)]);
      const bf16x8 qf1 = *reinterpret_cast<const bf16x8*>(
          &ql[(tl * 64 + 32 + 8 * l4) ^ ((tl & 7) << 3)]);
      f32x4 d = f32x4{0.f, 0.f, 0.f, 0.f};
      d = mfma16(ka0, qf0, d);
      d = mfma16(ka1, qf1, d);
      if (masked) {
        const int t = t0 + 16 * c + l15;
        const int sb = sw + 4 * l4;
#pragma unroll
        for (int r = 0; r < 4; ++r)
          if (t >= sb + r) cs[r] += __expf(d[r] * kScale);
      } else {
#pragma unroll
        for (int r = 0; r < 4; ++r) cs[r] += __expf(d[r] * kScale);
      }
    }
  }
  // reduce over the 16 t-lanes, write partial (unconditional; zero if no work)
#pragma unroll
  for (int r = 0; r < 4; ++r) {
    float v = cs[r];
    v += __shfl_xor(v, 1, 64);
    v += __shfl_xor(v, 2, 64);
    v += __shfl_xor(v, 4, 64);
    v += __shfl_xor(v, 8, 64);
    if (l15 == 0) lpart[(size_t)q4 * (kB * kT) + bT + sw + 4 * l4 + r] = v;
  }
}

// K2b: l = lp0 + lp1 + lp2 + lp3 (fixed order -> deterministic)
__global__ __launch_bounds__(256) void lcombine_kernel(
    const float* __restrict__ lpart, float* __restrict__ lG) {
  const size_t i = ((size_t)blockIdx.x * 256 + threadIdx.x) * 4;
  const float4 p0 = *reinterpret_cast<const float4*>(lpart + i);
  const float4 p1 = *reinterpret_cast<const float4*>(lpart + 16384 + i);
  const float4 p2 = *reinterpret_cast<const float4*>(lpart + 32768 + i);
  const float4 p3 = *reinterpret_cast<const float4*>(lpart + 49152 + i);
  float4 s;
  s.x = p0.x + p1.x + p2.x + p3.x;
  s.y = p0.y + p1.y + p2.y + p3.y;
  s.z = p0.z + p1.z + p2.z + p3.z;
  s.w = p0.w + p1.w + p2.w + p3.w;
  *reinterpret_cast<float4*>(lG + i) = s;
}

// K3a: partial PV over one s-quarter.  Block = (b, 128-row t-tile tt, quarter
// q4): 512 blocks x 8 waves.  Per s-tile of 64: cooperative LDS stage of
// k[64][64] + v^T[64][64], swapped QK^T -> (exp * rcp(l)) -> shuffle
// transpose -> PV.  1/l folded here.  part[q4][b][t][h].
__global__ __launch_bounds__(512, 4) void out_part_kernel(
    const u16* __restrict__ qb, const u16* __restrict__ kb, const u16* __restrict__ vt,
    const float* __restrict__ lG, float* __restrict__ part) {
  __shared__ u16 kl[64 * 64];  // 8 KiB, XOR-swizzled
  __shared__ u16 vl[64 * 64];  // 8 KiB, XOR-swizzled
  const int bid = blockIdx.x;
  const int b = bid & 7;            // batch-per-XCD L2 locality
  const int q4 = (bid >> 3) & 3;    // s-quarter
  const int tt = bid >> 5;          // 0..15
  const int t0 = tt * 128;
  const int tid = threadIdx.x;
  const int lane = tid & 63, w = tid >> 6;
  const int l15 = lane & 15, l4 = lane >> 4;
  const size_t bT = (size_t)b * kT;
  const int sA = l15 + 32 * (l4 & 1);
  const int sB = sA + 16;
  const bool hi = l4 >= 2;
  const int srow = tid >> 3, sc8 = (tid & 7) * 8;
  const int sidx = (srow * 64 + sc8) ^ ((srow & 7) << 3);

  const int tw = t0 + 16 * w;       // wave's first t-row
  const u16* qp = qb + (bT + tw + l15) * 64 + 8 * l4;
  const bf16x8 qf0 = *reinterpret_cast<const bf16x8*>(qp);
  const bf16x8 qf1 = *reinterpret_cast<const bf16x8*>(qp + 32);

  f32x4 acc[4];
#pragma unroll
  for (int nf = 0; nf < 4; ++nf) acc[nf] = f32x4{0.f, 0.f, 0.f, 0.f};

  const int js0 = q4 * 8;
  const int js1 = min(js0 + 8, 2 * tt + 2);
  for (int js = js0; js < js1; ++js) {
    const int s0 = js * 64;
    __syncthreads();  // previous iteration done reading LDS
    *reinterpret_cast<uint4*>(&kl[sidx]) =
        *reinterpret_cast<const uint4*>(&kb[(bT + s0 + srow) * 64 + sc8]);
    *reinterpret_cast<uint4*>(&vl[sidx]) =
        *reinterpret_cast<const uint4*>(&vt[(size_t)(b * 64 + srow) * kT + s0 + sc8]);
    __syncthreads();  // stage visible
    if (tw + 15 < s0) continue;  // wave entirely below this s-tile

    // per-lane 1/l for rows s = s0+16jf+4l4+r (issued early)
    float4 lv[4];
#pragma unroll
    for (int jf = 0; jf < 4; ++jf)
      lv[jf] = *reinterpret_cast<const float4*>(&lG[bT + s0 + 16 * jf + 4 * l4]);

    // QK^T (swapped): kf from LDS; D[s][t], row s = s0+16jf+4l4+r, col t = tw+l15
    unsigned pk0[4], pk1[4];
    const int t = tw + l15;
    const bool masked = (s0 + 63 > tw);  // wave-uniform
#pragma unroll
    for (int jf = 0; jf < 4; ++jf) {
      const int krow = 16 * jf + l15;
      const bf16x8 kf0 = *reinterpret_cast<const bf16x8*>(
          &kl[(krow * 64 + 8 * l4) ^ ((krow & 7) << 3)]);
      const bf16x8 kf1 = *reinterpret_cast<const bf16x8*>(
          &kl[(krow * 64 + 32 + 8 * l4) ^ ((krow & 7) << 3)]);
      f32x4 d = f32x4{0.f, 0.f, 0.f, 0.f};
      d = mfma16(kf0, qf0, d);
      d = mfma16(kf1, qf1, d);
      const float rl0 = __builtin_amdgcn_rcpf(lv[jf].x);
      const float rl1 = __builtin_amdgcn_rcpf(lv[jf].y);
      const float rl2 = __builtin_amdgcn_rcpf(lv[jf].z);
      const float rl3 = __builtin_amdgcn_rcpf(lv[jf].w);
      float p[4];
      if (masked) {
        const int sb = s0 + 16 * jf + 4 * l4;
        p[0] = (t >= sb + 0) ? __expf(d[0] * kScale) * rl0 : 0.f;
        p[1] = (t >= sb + 1) ? __expf(d[1] * kScale) * rl1 : 0.f;
        p[2] = (t >= sb + 2) ? __expf(d[2] * kScale) * rl2 : 0.f;
        p[3] = (t >= sb + 3) ? __expf(d[3] * kScale) * rl3 : 0.f;
      } else {
        p[0] = __expf(d[0] * kScale) * rl0;
        p[1] = __expf(d[1] * kScale) * rl1;
        p[2] = __expf(d[2] * kScale) * rl2;
        p[3] = __expf(d[3] * kScale) * rl3;
      }
      pk0[jf] = (unsigned)f2bu(p[0]) | ((unsigned)f2bu(p[1]) << 16);
      pk1[jf] = (unsigned)f2bu(p[2]) | ((unsigned)f2bu(p[3]) << 16);
    }
    // chunk 0 (s_loc 0..31): shuffle-transpose + PV from LDS v^T
    {
      const unsigned a0 = __shfl(pk0[0], sA), a1 = __shfl(pk1[0], sA);
      const unsigned a2 = __shfl(pk0[0], sB), a3 = __shfl(pk1[0], sB);
      const unsigned b0 = __shfl(pk0[1], sA), b1 = __shfl(pk1[1], sA);
      const unsigned b2 = __shfl(pk0[1], sB), b3 = __shfl(pk1[1], sB);
      uint4 pw;
      pw.x = hi ? b0 : a0; pw.y = hi ? b1 : a1;
      pw.z = hi ? b2 : a2; pw.w = hi ? b3 : a3;
      const bf16x8 pa = *reinterpret_cast<const bf16x8*>(&pw);
#pragma unroll
      for (int nf = 0; nf < 4; ++nf) {
        const int vrow = 16 * nf + l15;
        const bf16x8 vf = *reinterpret_cast<const bf16x8*>(
            &vl[(vrow * 64 + 8 * l4) ^ ((vrow & 7) << 3)]);
        acc[nf] = mfma16(pa, vf, acc[nf]);
      }
    }
    // chunk 1 (s_loc 32..63)
    {
      const unsigned a0 = __shfl(pk0[2], sA), a1 = __shfl(pk1[2], sA);
      const unsigned a2 = __shfl(pk0[2], sB), a3 = __shfl(pk1[2], sB);
      const unsigned b0 = __shfl(pk0[3], sA), b1 = __shfl(pk1[3], sA);
      const unsigned b2 = __shfl(pk0[3], sB), b3 = __shfl(pk1[3], sB);
      uint4 pw;
      pw.x = hi ? b0 : a0; pw.y = hi ? b1 : a1;
      pw.z = hi ? b2 : a2; pw.w = hi ? b3 : a3;
      const bf16x8 pa = *reinterpret_cast<const bf16x8*>(&pw);
#pragma unroll
      for (int nf = 0; nf < 4; ++nf) {
        const int vrow = 16 * nf + l15;
        const bf16x8 vf = *reinterpret_cast<const bf16x8*>(
            &vl[(vrow * 64 + 32 + 8 * l4) ^ ((vrow & 7) << 3)]);
        acc[nf] = mfma16(pa, vf, acc[nf]);
      }
    }
  }
  // write partial tile (unconditional; zero if no work)
  float* pb = part + (size_t)(q4 * 8 + b) * kT * kH;
#pragma unroll
  for (int nf = 0; nf < 4; ++nf) {
#pragma unroll
    for (int r = 0; r < 4; ++r) {
      pb[(size_t)(tw + 4 * l4 + r) * 64 + 16 * nf + l15] = acc[nf][r];
    }
  }
}

// K3b: out = part0 + part1 + part2 + part3 (fixed order -> deterministic)
__global__ __launch_bounds__(256) void combine_kernel(
    const float* __restrict__ part, float* __restrict__ out) {
  const size_t i = ((size_t)blockIdx.x * 256 + threadIdx.x) * 4;
  const float4 p0 = *reinterpret_cast<const float4*>(part + i);
  const float4 p1 = *reinterpret_cast<const float4*>(part + 1048576 + i);
  const float4 p2 = *reinterpret_cast<const float4*>(part + 2097152 + i);
  const float4 p3 = *reinterpret_cast<const float4*>(part + 3145728 + i);
  float4 s;
  s.x = p0.x + p1.x + p2.x + p3.x;
  s.y = p0.y + p1.y + p2.y + p3.y;
  s.z = p0.z + p1.z + p2.z + p3.z;
  s.w = p0.w + p1.w + p2.w + p3.w;
  *reinterpret_cast<float4*>(out + i) = s;
}

}  // namespace

extern "C" void kernel_launch(void* const* d_in, const int* in_sizes, int n_in,
                              void* d_out, int out_size, void* d_ws, size_t ws_size,
                              hipStream_t stream) {
  const float* x = (const float*)d_in[0];
  const float* Wk = (const float*)d_in[1];
  const float* Wq = (const float*)d_in[2];
  const float* Wv = (const float*)d_in[3];
  u16* wsu = (u16*)d_ws;
  u16* Wt = wsu + kWtOff;
  u16* qb = wsu + kQbOff;
  u16* kb = wsu + kKbOff;
  u16* vt = wsu + kVtOff;
  float* lG = (float*)(wsu + kLOff);
  float* part = (float*)(wsu + kPartOff);
  float* lpart = (float*)(wsu + kLPartOff);
  float* out = (float*)d_out;

  wt_kernel<<<dim3(16, 3), dim3(256), 0, stream>>>(Wk, Wq, Wv, Wt);
  qkv_kernel<<<dim3(kB * kT / 32), dim3(256), 0, stream>>>(x, Wt, qb, kb, vt);
  colsum_part_kernel<<<dim3(512), dim3(512), 0, stream>>>(qb, kb, lpart);
  lcombine_kernel<<<dim3(16), dim3(256), 0, stream>>>(lpart, lG);
  out_part_kernel<<<dim3(512), dim3(512), 0, stream>>>(qb, kb, vt, lG, part);
  combine_kernel<<<dim3(1024), dim3(256), 0, stream>>>(part, out);
}